// Round 10
// baseline (170.592 us; speedup 1.0000x reference)
//
#include <hip/hip_runtime.h>

// FeaturePropagationV2: 3-NN inverse-distance interpolation + Linear, fused as:
//   G = feature2 @ W.T          (precomputed once, 8192x256)
//   out[i] = sum_k w_k * G[idx_k] + b
//
// kNN with the WHOLE coarse cloud in LDS (128 KB), lane=query orientation:
//   Stage  : block cooperatively copies pack[8192] (float4) into LDS.
//   Phase 1: wave w samples first 256 pts of its range via uniform broadcast
//            ds_read, sloppy batch-min top-4 -> per-query threshold.
//   Phase 2: wave w scans its 1024-pt range, 5 VALU/pt from uniform LDS
//            reads; survivors (m <= t) pushed to per-(query,wave) rings.
//   Select : exact reference-f32 re-score, stable (d2,idx) top-3 (validated).
// Registers stay tiny (no resident slab) — ends the r5-r9 allocator fight.
// mdl4 aliases ring_raw; mdl/mil alias slab_raw (barrier-separated phases).

#define FLT_BIG 3.402823466e+38f
#define CAP     16
#define MARGIN  3e-5f

__global__ __launch_bounds__(256) void prep_kernel(const float* __restrict__ xyz2,
                                                   float4* __restrict__ pack, int N2) {
    int j = blockIdx.x * 256 + threadIdx.x;
    if (j < N2) {
        float x = xyz2[3 * j + 0];
        float y = xyz2[3 * j + 1];
        float z = xyz2[3 * j + 2];
        float4 p;
        p.x = x; p.y = y; p.z = z;
        p.w = 0.5f * (x * x + y * y + z * z);   // scan metric only
        pack[j] = p;
    }
}

// C[m][n] = sum_k A[m][k] * B[n][k]   (unchanged)
__global__ __launch_bounds__(256) void gemm_nt_f32(const float* __restrict__ A,
                                                   const float* __restrict__ B,
                                                   float* __restrict__ C,
                                                   int M, int N, int K) {
    __shared__ float As[64][68];
    __shared__ float Bs[64][68];

    const int t  = threadIdx.x;
    const int tx = t & 15;
    const int ty = t >> 4;
    const int bm = blockIdx.x * 64;
    const int bn = blockIdx.y * 64;

    float acc[4][4] = {{0.f}};

    for (int kt = 0; kt < K; kt += 64) {
#pragma unroll
        for (int rr = 0; rr < 4; ++rr) {
            int r = ty + 16 * rr;
            int c = tx * 4;
            float4 av = *(const float4*)(A + (size_t)(bm + r) * K + kt + c);
            As[c + 0][r] = av.x;
            As[c + 1][r] = av.y;
            As[c + 2][r] = av.z;
            As[c + 3][r] = av.w;
            float4 bv = *(const float4*)(B + (size_t)(bn + r) * K + kt + c);
            Bs[c + 0][r] = bv.x;
            Bs[c + 1][r] = bv.y;
            Bs[c + 2][r] = bv.z;
            Bs[c + 3][r] = bv.w;
        }
        __syncthreads();

#pragma unroll 8
        for (int k = 0; k < 64; ++k) {
            float4 a4 = *(const float4*)&As[k][ty * 4];
            float4 b4 = *(const float4*)&Bs[k][tx * 4];
            float a[4] = {a4.x, a4.y, a4.z, a4.w};
            float b[4] = {b4.x, b4.y, b4.z, b4.w};
#pragma unroll
            for (int i = 0; i < 4; ++i)
#pragma unroll
                for (int j = 0; j < 4; ++j)
                    acc[i][j] = fmaf(a[i], b[j], acc[i][j]);
        }
        __syncthreads();
    }

#pragma unroll
    for (int i = 0; i < 4; ++i) {
        float4 v;
        v.x = acc[i][0]; v.y = acc[i][1]; v.z = acc[i][2]; v.w = acc[i][3];
        *(float4*)(C + (size_t)(bm + ty * 4 + i) * N + bn + tx * 4) = v;
    }
}

// branchless value-only sorted top-4 insert: 7 min/max ops
#define TOP4V_INSERT(mv)                                           \
    do {                                                           \
        float _x  = (mv);                                          \
        float _n0 = fminf(b0, _x);  float _y0 = fmaxf(b0, _x); b0 = _n0; \
        float _n1 = fminf(b1, _y0); float _y1 = fmaxf(b1, _y0); b1 = _n1; \
        float _n2 = fminf(b2, _y1); float _y2 = fmaxf(b2, _y1); b2 = _n2; \
        b3 = fminf(b3, _y2);                                       \
    } while (0)

// stable (dd, j) insert into sorted top-3 (d0<=d1<=d2v), idx tiebreak
#define TOP3JD_INSERT(dd, j)                                       \
    do {                                                           \
        bool lt2 = ((dd) < d2v) || ((dd) == d2v && (j) < j2);      \
        if (lt2) {                                                 \
            bool lt1 = ((dd) < d1) || ((dd) == d1 && (j) < j1);    \
            if (lt1) {                                             \
                d2v = d1; j2 = j1;                                 \
                bool lt0 = ((dd) < d0) || ((dd) == d0 && (j) < j0);\
                if (lt0) { d1 = d0; j1 = j0; d0 = (dd); j0 = (j); }\
                else     { d1 = (dd); j1 = (j); }                  \
            } else { d2v = (dd); j2 = (j); }                       \
        }                                                          \
    } while (0)

// Block: 512 threads = 8 waves, owns 64 fine points (queries, lane=query).
// Wave w scans coarse range [w*1024,(w+1)*1024) from the LDS-resident cloud.
__global__ __launch_bounds__(512) void knn_gather(const float* __restrict__ xyz1,
                                                  const float4* __restrict__ pack,
                                                  const float4* __restrict__ G4,    // [N2*64]
                                                  const float4* __restrict__ bias4, // [64]
                                                  float4* __restrict__ out4,        // [N1*64]
                                                  int N2) {
    // 131072 B: whole coarse cloud; later (stage A, after barrier) the first
    // 12800 B are reused as mdl[64][25] (f32) + mil[64][25] (i32).
    __shared__ __align__(16) unsigned char slab_raw[131072];
    // 16512 B: rings [64][129] u16; during phase 1 reused as mdl4[64][33] f32.
    __shared__ __align__(16) unsigned char ring_raw[16512];
    __shared__ float          thr[64];
    __shared__ unsigned short cnts[64][8];
    __shared__ float          swgt[64][3];
    __shared__ int            sidx[64][3];

    float4*         slab = (float4*)slab_raw;                    // [8192]
    float*          mdl  = (float*)slab_raw;                     // [64][25]
    int*            mil  = (int*)(slab_raw + 6400);              // [64][25]
    unsigned short* ring = (unsigned short*)ring_raw;            // [64][129]
    float*          mdl4 = (float*)ring_raw;                     // [64][33]

    const int tid  = threadIdx.x;
    const int wave = __builtin_amdgcn_readfirstlane(tid >> 6);
    const int lane = tid & 63;
    const int fine = blockIdx.x * 64 + lane;

    const float qx = xyz1[3 * fine + 0];
    const float qy = xyz1[3 * fine + 1];
    const float qz = xyz1[3 * fine + 2];

    const int base = wave * 1024;              // this wave's point range

    // ---- Stage: cooperative copy of the whole cloud into LDS ----
#pragma unroll 4
    for (int i = 0; i < 16; ++i) {
        int idx = i * 512 + tid;
        slab[idx] = pack[idx];
    }
    __syncthreads();

    // ---- Phase 1 (lane=query): batch-min(4) sloppy top-4 over 256 sample
    {
        float b0 = FLT_BIG, b1 = FLT_BIG, b2 = FLT_BIG, b3 = FLT_BIG;
        const float4* sp = slab + base;
#pragma unroll 2
        for (int k = 0; k < 256; k += 4) {
            float4 p0 = sp[k + 0];              // uniform addr -> broadcast
            float4 p1 = sp[k + 1];
            float4 p2 = sp[k + 2];
            float4 p3 = sp[k + 3];
            float m0 = p0.w - fmaf(qx, p0.x, fmaf(qy, p0.y, qz * p0.z));
            float m1 = p1.w - fmaf(qx, p1.x, fmaf(qy, p1.y, qz * p1.z));
            float m2 = p2.w - fmaf(qx, p2.x, fmaf(qy, p2.y, qz * p2.z));
            float m3 = p3.w - fmaf(qx, p3.x, fmaf(qy, p3.y, qz * p3.z));
            float mm = fminf(fminf(m0, m1), fminf(m2, m3));  // batch-min:
            TOP4V_INSERT(mm);                   // under-maintains -> larger t (safe)
        }
        mdl4[lane * 33 + wave * 4 + 0] = b0;
        mdl4[lane * 33 + wave * 4 + 1] = b1;
        mdl4[lane * 33 + wave * 4 + 2] = b2;
        mdl4[lane * 33 + wave * 4 + 3] = b3;
    }
    __syncthreads();

    if (tid < 64) {
        float b0 = FLT_BIG, b1 = FLT_BIG, b2 = FLT_BIG, b3 = FLT_BIG;
#pragma unroll
        for (int w = 0; w < 8; ++w)
#pragma unroll
            for (int k = 0; k < 4; ++k)
                TOP4V_INSERT(mdl4[tid * 33 + w * 4 + k]);
        thr[tid] = b3 + MARGIN;   // sample-4th >= true-3rd; margin covers
    }                              // formula-rounding differences vs ref d2
    __syncthreads();

    // ---- Phase 2 (lane=query): scan own range from LDS, threshold filter ----
    {
        const float t = thr[lane];
        const float4* sp = slab + base;
        unsigned short* myring = ring + lane * 129 + wave * CAP;
        int cnt = 0;
#pragma unroll 1
        for (int jj = 0; jj < 1024; jj += 4) {
            float4 p0 = sp[jj + 0];             // uniform -> broadcast, no conflict
            float4 p1 = sp[jj + 1];
            float4 p2 = sp[jj + 2];
            float4 p3 = sp[jj + 3];
            float m0 = p0.w - fmaf(qx, p0.x, fmaf(qy, p0.y, qz * p0.z));
            float m1 = p1.w - fmaf(qx, p1.x, fmaf(qy, p1.y, qz * p1.z));
            float m2 = p2.w - fmaf(qx, p2.x, fmaf(qy, p2.y, qz * p2.z));
            float m3 = p3.w - fmaf(qx, p3.x, fmaf(qy, p3.y, qz * p3.z));
            bool a0 = m0 <= t;
            bool a1 = m1 <= t;
            bool a2 = m2 <= t;
            bool a3 = m3 <= t;
            if (__any(a0 | a1 | a2 | a3)) {     // taken ~40% of groups
                if (a0) { myring[min(cnt, CAP - 1)] = (unsigned short)(base + jj + 0); ++cnt; }
                if (a1) { myring[min(cnt, CAP - 1)] = (unsigned short)(base + jj + 1); ++cnt; }
                if (a2) { myring[min(cnt, CAP - 1)] = (unsigned short)(base + jj + 2); ++cnt; }
                if (a3) { myring[min(cnt, CAP - 1)] = (unsigned short)(base + jj + 3); ++cnt; }
            }
        }
        cnts[lane][wave] = (unsigned short)min(cnt, CAP);
    }
    __syncthreads();

    // ---- Selection stage A: thread (q,w) scores ring[q][w] with the exact
    //      reference-f32 formula, keeps stable top-3 (writes alias slab) ----
    {
        const int q  = tid >> 3;
        const int w  = tid & 7;
        const int fq = blockIdx.x * 64 + q;
        const float sqx = xyz1[3 * fq + 0];
        const float sqy = xyz1[3 * fq + 1];
        const float sqz = xyz1[3 * fq + 2];
        // q_sq = (qx*qx + qy*qy) + qz*qz  (no contraction, ref rounding)
        const float qsq = __fadd_rn(__fadd_rn(__fmul_rn(sqx, sqx), __fmul_rn(sqy, sqy)),
                                    __fmul_rn(sqz, sqz));
        float d0 = FLT_BIG, d1 = FLT_BIG, d2v = FLT_BIG;
        int   j0 = 0x7fffffff, j1 = 0x7fffffff, j2 = 0x7fffffff;
        const int n = (int)cnts[q][w];
#pragma unroll 1
        for (int e = 0; e < n; ++e) {
            const int j = ring[q * 129 + w * CAP + e];
            float4 p = pack[j];                 // global; pack is L2-resident
            // x2_sq = (x*x + y*y) + z*z
            float x2s = __fadd_rn(__fadd_rn(__fmul_rn(p.x, p.x), __fmul_rn(p.y, p.y)),
                                  __fmul_rn(p.z, p.z));
            // dot = fma(qz,z, fma(qy,y, rn(qx*x)))  — BLAS k-ascending chain
            float dot = __fmaf_rn(sqz, p.z, __fmaf_rn(sqy, p.y, __fmul_rn(sqx, p.x)));
            // d2 = (q_sq + x2_sq) - 2*dot
            float dd = __fsub_rn(__fadd_rn(qsq, x2s), __fmul_rn(2.0f, dot));
            TOP3JD_INSERT(dd, j);
        }
        mdl[q * 25 + w * 3 + 0] = d0;  mdl[q * 25 + w * 3 + 1] = d1;  mdl[q * 25 + w * 3 + 2] = d2v;
        mil[q * 25 + w * 3 + 0] = j0;  mil[q * 25 + w * 3 + 1] = j1;  mil[q * 25 + w * 3 + 2] = j2;
    }
    __syncthreads();

    // ---- Selection stage B: one thread per query merges 8x3, weights ----
    if (tid < 64) {
        float d0 = FLT_BIG, d1 = FLT_BIG, d2v = FLT_BIG;
        int   j0 = 0x7fffffff, j1 = 0x7fffffff, j2 = 0x7fffffff;
#pragma unroll
        for (int w = 0; w < 8; ++w)
#pragma unroll
            for (int k = 0; k < 3; ++k) {
                float dd = mdl[tid * 25 + w * 3 + k];
                int   j  = mil[tid * 25 + w * 3 + k];
                TOP3JD_INSERT(dd, j);
            }
        // f32 inverse-distance weights, reference op order
        float w0 = 1.0f / (__fadd_rn(sqrtf(fmaxf(d0,  1e-12f)), 1e-8f));
        float w1 = 1.0f / (__fadd_rn(sqrtf(fmaxf(d1,  1e-12f)), 1e-8f));
        float w2 = 1.0f / (__fadd_rn(sqrtf(fmaxf(d2v, 1e-12f)), 1e-8f));
        float wsum = __fadd_rn(__fadd_rn(w0, w1), w2);
        swgt[tid][0] = w0 / wsum; sidx[tid][0] = j0;
        swgt[tid][1] = w1 / wsum; sidx[tid][1] = j1;
        swgt[tid][2] = w2 / wsum; sidx[tid][2] = j2;
    }
    __syncthreads();

    // ---- Gather: out[fine] = w0*G[j0] + w1*G[j1] + w2*G[j2] + b ----
    const float4 bb = bias4[lane];
#pragma unroll
    for (int p = 0; p < 8; ++p) {
        int fl = wave * 8 + p;
        float w0 = swgt[fl][0];
        float w1 = swgt[fl][1];
        float w2 = swgt[fl][2];
        int j0 = sidx[fl][0];
        int j1 = sidx[fl][1];
        int j2 = sidx[fl][2];
        float4 g0 = G4[(size_t)j0 * 64 + lane];
        float4 g1 = G4[(size_t)j1 * 64 + lane];
        float4 g2 = G4[(size_t)j2 * 64 + lane];
        float4 o;
        o.x = fmaf(w0, g0.x, fmaf(w1, g1.x, fmaf(w2, g2.x, bb.x)));
        o.y = fmaf(w0, g0.y, fmaf(w1, g1.y, fmaf(w2, g2.y, bb.y)));
        o.z = fmaf(w0, g0.z, fmaf(w1, g1.z, fmaf(w2, g2.z, bb.z)));
        o.w = fmaf(w0, g0.w, fmaf(w1, g1.w, fmaf(w2, g2.w, bb.w)));
        out4[(size_t)(blockIdx.x * 64 + fl) * 64 + lane] = o;
    }
}

extern "C" void kernel_launch(void* const* d_in, const int* in_sizes, int n_in,
                              void* d_out, int out_size, void* d_ws, size_t ws_size,
                              hipStream_t stream) {
    const float* xyz1 = (const float*)d_in[0];
    const float* xyz2 = (const float*)d_in[1];
    // d_in[2] = feature1 (unused by the reference computation)
    const float* f2   = (const float*)d_in[3];
    const float* W    = (const float*)d_in[6];
    const float* bias = (const float*)d_in[7];

    const int N1  = in_sizes[0] / 3;   // 32768
    const int N2  = in_sizes[1] / 3;   // 8192
    const int C   = in_sizes[3] / N2;  // 256
    const int OUT = in_sizes[7];       // 256

    float*  G    = (float*)d_ws;                                   // N2*OUT f32 = 8 MB
    float4* pack = (float4*)((char*)d_ws + (size_t)N2 * OUT * 4);  // N2 float4 = 128 KB

    prep_kernel<<<(N2 + 255) / 256, 256, 0, stream>>>(xyz2, pack, N2);

    dim3 ggrid(N2 / 64, OUT / 64);
    gemm_nt_f32<<<ggrid, 256, 0, stream>>>(f2, W, G, N2, OUT, C);

    knn_gather<<<N1 / 64, 512, 0, stream>>>(xyz1, pack, (const float4*)G,
                                            (const float4*)bias, (float4*)d_out, N2);
}

// Round 11
// 133.910 us; speedup vs baseline: 1.2739x; 1.2739x over previous
//
#include <hip/hip_runtime.h>

// FeaturePropagationV2: 3-NN inverse-distance interpolation + Linear, fused as:
//   G = feature2 @ W.T          (precomputed once, 8192x256)
//   out[i] = sum_k w_k * G[idx_k] + b
//
// kNN, lane=query, half-cloud LDS double-pass (occupancy-preserving):
//   Stage h: 4096 pts (64 KB) of the cloud in LDS; wave w scans slab-local
//            [w*512,(w+1)*512) with uniform broadcast ds_read, 5 VALU/pt;
//            survivor cnt persists in registers across the two passes.
//   Phase 1: sample = first 256 pts of each wave's half-0 range (2048 total),
//            sloppy batch-min top-4 -> per-query threshold.
//   Select : exact reference-f32 re-score, stable (d2,idx) top-3 (validated).
// LDS ~80.9 KB/block -> 2 blocks/CU (4 waves/SIMD). Aliases (barrier-safe):
//   slab_raw <- mdl/mil (stage A);  ring_raw <- mdl4 (phase 1), swgt/sidx (B).

#define FLT_BIG 3.402823466e+38f
#define CAP     14
#define RROW    (8 * CAP + 1)     // 113 u16 = 226 B row, bank-spread
#define MARGIN  3e-5f

__global__ __launch_bounds__(256) void prep_kernel(const float* __restrict__ xyz2,
                                                   float4* __restrict__ pack, int N2) {
    int j = blockIdx.x * 256 + threadIdx.x;
    if (j < N2) {
        float x = xyz2[3 * j + 0];
        float y = xyz2[3 * j + 1];
        float z = xyz2[3 * j + 2];
        float4 p;
        p.x = x; p.y = y; p.z = z;
        p.w = 0.5f * (x * x + y * y + z * z);   // scan metric only
        pack[j] = p;
    }
}

// C[m][n] = sum_k A[m][k] * B[n][k]   (unchanged)
__global__ __launch_bounds__(256) void gemm_nt_f32(const float* __restrict__ A,
                                                   const float* __restrict__ B,
                                                   float* __restrict__ C,
                                                   int M, int N, int K) {
    __shared__ float As[64][68];
    __shared__ float Bs[64][68];

    const int t  = threadIdx.x;
    const int tx = t & 15;
    const int ty = t >> 4;
    const int bm = blockIdx.x * 64;
    const int bn = blockIdx.y * 64;

    float acc[4][4] = {{0.f}};

    for (int kt = 0; kt < K; kt += 64) {
#pragma unroll
        for (int rr = 0; rr < 4; ++rr) {
            int r = ty + 16 * rr;
            int c = tx * 4;
            float4 av = *(const float4*)(A + (size_t)(bm + r) * K + kt + c);
            As[c + 0][r] = av.x;
            As[c + 1][r] = av.y;
            As[c + 2][r] = av.z;
            As[c + 3][r] = av.w;
            float4 bv = *(const float4*)(B + (size_t)(bn + r) * K + kt + c);
            Bs[c + 0][r] = bv.x;
            Bs[c + 1][r] = bv.y;
            Bs[c + 2][r] = bv.z;
            Bs[c + 3][r] = bv.w;
        }
        __syncthreads();

#pragma unroll 8
        for (int k = 0; k < 64; ++k) {
            float4 a4 = *(const float4*)&As[k][ty * 4];
            float4 b4 = *(const float4*)&Bs[k][tx * 4];
            float a[4] = {a4.x, a4.y, a4.z, a4.w};
            float b[4] = {b4.x, b4.y, b4.z, b4.w};
#pragma unroll
            for (int i = 0; i < 4; ++i)
#pragma unroll
                for (int j = 0; j < 4; ++j)
                    acc[i][j] = fmaf(a[i], b[j], acc[i][j]);
        }
        __syncthreads();
    }

#pragma unroll
    for (int i = 0; i < 4; ++i) {
        float4 v;
        v.x = acc[i][0]; v.y = acc[i][1]; v.z = acc[i][2]; v.w = acc[i][3];
        *(float4*)(C + (size_t)(bm + ty * 4 + i) * N + bn + tx * 4) = v;
    }
}

// branchless value-only sorted top-4 insert: 7 min/max ops
#define TOP4V_INSERT(mv)                                           \
    do {                                                           \
        float _x  = (mv);                                          \
        float _n0 = fminf(b0, _x);  float _y0 = fmaxf(b0, _x); b0 = _n0; \
        float _n1 = fminf(b1, _y0); float _y1 = fmaxf(b1, _y0); b1 = _n1; \
        float _n2 = fminf(b2, _y1); float _y2 = fmaxf(b2, _y1); b2 = _n2; \
        b3 = fminf(b3, _y2);                                       \
    } while (0)

// stable (dd, j) insert into sorted top-3 (d0<=d1<=d2v), idx tiebreak
#define TOP3JD_INSERT(dd, j)                                       \
    do {                                                           \
        bool lt2 = ((dd) < d2v) || ((dd) == d2v && (j) < j2);      \
        if (lt2) {                                                 \
            bool lt1 = ((dd) < d1) || ((dd) == d1 && (j) < j1);    \
            if (lt1) {                                             \
                d2v = d1; j2 = j1;                                 \
                bool lt0 = ((dd) < d0) || ((dd) == d0 && (j) < j0);\
                if (lt0) { d1 = d0; j1 = j0; d0 = (dd); j0 = (j); }\
                else     { d1 = (dd); j1 = (j); }                  \
            } else { d2v = (dd); j2 = (j); }                       \
        }                                                          \
    } while (0)

// Block: 512 threads = 8 waves, owns 64 fine points (queries, lane=query).
// Pass h stages global [h*4096,(h+1)*4096) in LDS; wave w scans slab-local
// [w*512,(w+1)*512).
__global__ __launch_bounds__(512) void knn_gather(const float* __restrict__ xyz1,
                                                  const float4* __restrict__ pack,
                                                  const float4* __restrict__ G4,    // [N2*64]
                                                  const float4* __restrict__ bias4, // [64]
                                                  float4* __restrict__ out4,        // [N1*64]
                                                  int N2) {
    // 65536 B: half cloud; in stage A the first 12800 B are reused as
    // mdl[64][25] f32 + mil[64][25] i32.
    __shared__ __align__(16) unsigned char slab_raw[65536];
    // 14464 B: rings [64][RROW] u16; phase 1 reuses as mdl4[64][33] f32;
    // stage B reuses as swgt[64][3] f32 + sidx[64][3] i32.
    __shared__ __align__(16) unsigned char ring_raw[64 * RROW * 2];
    __shared__ float         thr[64];
    __shared__ unsigned char cnts[64][8];

    float4*         slab = (float4*)slab_raw;                    // [4096]
    float*          mdl  = (float*)slab_raw;                     // [64][25]
    int*            mil  = (int*)(slab_raw + 6400);              // [64][25]
    unsigned short* ring = (unsigned short*)ring_raw;            // [64][RROW]
    float*          mdl4 = (float*)ring_raw;                     // [64][33]
    float*          swgt = (float*)ring_raw;                     // [64][3]
    int*            sidx = (int*)(ring_raw + 768);               // [64][3]

    const int tid  = threadIdx.x;
    const int wave = __builtin_amdgcn_readfirstlane(tid >> 6);
    const int lane = tid & 63;
    const int fine = blockIdx.x * 64 + lane;

    const float qx = xyz1[3 * fine + 0];
    const float qy = xyz1[3 * fine + 1];
    const float qz = xyz1[3 * fine + 2];

    // ---- Stage half 0 ----
#pragma unroll
    for (int i = 0; i < 8; ++i) {
        int idx = i * 512 + tid;
        slab[idx] = pack[idx];
    }
    __syncthreads();

    // ---- Phase 1 (lane=query): batch-min(4) sloppy top-4 over wave's
    //      first 256 pts of half-0 range (2048 sampled block-wide) ----
    {
        float b0 = FLT_BIG, b1 = FLT_BIG, b2 = FLT_BIG, b3 = FLT_BIG;
        const float4* sp = slab + wave * 512;
#pragma unroll 2
        for (int k = 0; k < 256; k += 4) {
            float4 p0 = sp[k + 0];              // uniform addr -> broadcast
            float4 p1 = sp[k + 1];
            float4 p2 = sp[k + 2];
            float4 p3 = sp[k + 3];
            float m0 = p0.w - fmaf(qx, p0.x, fmaf(qy, p0.y, qz * p0.z));
            float m1 = p1.w - fmaf(qx, p1.x, fmaf(qy, p1.y, qz * p1.z));
            float m2 = p2.w - fmaf(qx, p2.x, fmaf(qy, p2.y, qz * p2.z));
            float m3 = p3.w - fmaf(qx, p3.x, fmaf(qy, p3.y, qz * p3.z));
            float mm = fminf(fminf(m0, m1), fminf(m2, m3));  // batch-min:
            TOP4V_INSERT(mm);                   // under-maintains -> larger t (safe)
        }
        mdl4[lane * 33 + wave * 4 + 0] = b0;
        mdl4[lane * 33 + wave * 4 + 1] = b1;
        mdl4[lane * 33 + wave * 4 + 2] = b2;
        mdl4[lane * 33 + wave * 4 + 3] = b3;
    }
    __syncthreads();

    if (tid < 64) {
        float b0 = FLT_BIG, b1 = FLT_BIG, b2 = FLT_BIG, b3 = FLT_BIG;
#pragma unroll
        for (int w = 0; w < 8; ++w)
#pragma unroll
            for (int k = 0; k < 4; ++k)
                TOP4V_INSERT(mdl4[tid * 33 + w * 4 + k]);
        thr[tid] = b3 + MARGIN;   // sample-4th >= true-3rd; margin covers
    }                              // formula-rounding differences vs ref d2
    __syncthreads();

    // ---- Phase 2 (lane=query): two half-cloud passes, threshold filter ----
    {
        const float t = thr[lane];
        unsigned short* myring = ring + lane * RROW + wave * CAP;
        int cnt = 0;                            // persists across passes
#pragma unroll 1
        for (int h = 0; h < 2; ++h) {
            if (h == 1) {                       // re-stage second half
                __syncthreads();                // everyone done with half 0
#pragma unroll
                for (int i = 0; i < 8; ++i) {
                    int idx = i * 512 + tid;
                    slab[idx] = pack[4096 + idx];
                }
                __syncthreads();
            }
            const float4* sp = slab + wave * 512;
            const int gbase = h * 4096 + wave * 512;   // global index base
#pragma unroll 2
            for (int jj = 0; jj < 512; jj += 4) {
                float4 p0 = sp[jj + 0];         // uniform -> broadcast
                float4 p1 = sp[jj + 1];
                float4 p2 = sp[jj + 2];
                float4 p3 = sp[jj + 3];
                float m0 = p0.w - fmaf(qx, p0.x, fmaf(qy, p0.y, qz * p0.z));
                float m1 = p1.w - fmaf(qx, p1.x, fmaf(qy, p1.y, qz * p1.z));
                float m2 = p2.w - fmaf(qx, p2.x, fmaf(qy, p2.y, qz * p2.z));
                float m3 = p3.w - fmaf(qx, p3.x, fmaf(qy, p3.y, qz * p3.z));
                bool a0 = m0 <= t;
                bool a1 = m1 <= t;
                bool a2 = m2 <= t;
                bool a3 = m3 <= t;
                if (__any(a0 | a1 | a2 | a3)) { // taken ~30% of groups
                    if (a0) { myring[min(cnt, CAP - 1)] = (unsigned short)(gbase + jj + 0); ++cnt; }
                    if (a1) { myring[min(cnt, CAP - 1)] = (unsigned short)(gbase + jj + 1); ++cnt; }
                    if (a2) { myring[min(cnt, CAP - 1)] = (unsigned short)(gbase + jj + 2); ++cnt; }
                    if (a3) { myring[min(cnt, CAP - 1)] = (unsigned short)(gbase + jj + 3); ++cnt; }
                }
            }
        }
        cnts[lane][wave] = (unsigned char)min(cnt, CAP);
    }
    __syncthreads();

    // ---- Selection stage A: thread (q,w) scores ring[q][w] with the exact
    //      reference-f32 formula, keeps stable top-3 (writes alias slab) ----
    {
        const int q  = tid >> 3;
        const int w  = tid & 7;
        const int fq = blockIdx.x * 64 + q;
        const float sqx = xyz1[3 * fq + 0];
        const float sqy = xyz1[3 * fq + 1];
        const float sqz = xyz1[3 * fq + 2];
        // q_sq = (qx*qx + qy*qy) + qz*qz  (no contraction, ref rounding)
        const float qsq = __fadd_rn(__fadd_rn(__fmul_rn(sqx, sqx), __fmul_rn(sqy, sqy)),
                                    __fmul_rn(sqz, sqz));
        float d0 = FLT_BIG, d1 = FLT_BIG, d2v = FLT_BIG;
        int   j0 = 0x7fffffff, j1 = 0x7fffffff, j2 = 0x7fffffff;
        const int n = (int)cnts[q][w];
#pragma unroll 1
        for (int e = 0; e < n; ++e) {
            const int j = ring[q * RROW + w * CAP + e];
            float4 p = pack[j];                 // global; pack is L2-resident
            // x2_sq = (x*x + y*y) + z*z
            float x2s = __fadd_rn(__fadd_rn(__fmul_rn(p.x, p.x), __fmul_rn(p.y, p.y)),
                                  __fmul_rn(p.z, p.z));
            // dot = fma(qz,z, fma(qy,y, rn(qx*x)))  — BLAS k-ascending chain
            float dot = __fmaf_rn(sqz, p.z, __fmaf_rn(sqy, p.y, __fmul_rn(sqx, p.x)));
            // d2 = (q_sq + x2_sq) - 2*dot
            float dd = __fsub_rn(__fadd_rn(qsq, x2s), __fmul_rn(2.0f, dot));
            TOP3JD_INSERT(dd, j);
        }
        mdl[q * 25 + w * 3 + 0] = d0;  mdl[q * 25 + w * 3 + 1] = d1;  mdl[q * 25 + w * 3 + 2] = d2v;
        mil[q * 25 + w * 3 + 0] = j0;  mil[q * 25 + w * 3 + 1] = j1;  mil[q * 25 + w * 3 + 2] = j2;
    }
    __syncthreads();

    // ---- Selection stage B: one thread per query merges 8x3, weights ----
    // (swgt/sidx alias ring_raw — ring is dead after stage A)
    if (tid < 64) {
        float d0 = FLT_BIG, d1 = FLT_BIG, d2v = FLT_BIG;
        int   j0 = 0x7fffffff, j1 = 0x7fffffff, j2 = 0x7fffffff;
#pragma unroll
        for (int w = 0; w < 8; ++w)
#pragma unroll
            for (int k = 0; k < 3; ++k) {
                float dd = mdl[tid * 25 + w * 3 + k];
                int   j  = mil[tid * 25 + w * 3 + k];
                TOP3JD_INSERT(dd, j);
            }
        // f32 inverse-distance weights, reference op order
        float w0 = 1.0f / (__fadd_rn(sqrtf(fmaxf(d0,  1e-12f)), 1e-8f));
        float w1 = 1.0f / (__fadd_rn(sqrtf(fmaxf(d1,  1e-12f)), 1e-8f));
        float w2 = 1.0f / (__fadd_rn(sqrtf(fmaxf(d2v, 1e-12f)), 1e-8f));
        float wsum = __fadd_rn(__fadd_rn(w0, w1), w2);
        swgt[tid * 3 + 0] = w0 / wsum; sidx[tid * 3 + 0] = j0;
        swgt[tid * 3 + 1] = w1 / wsum; sidx[tid * 3 + 1] = j1;
        swgt[tid * 3 + 2] = w2 / wsum; sidx[tid * 3 + 2] = j2;
    }
    __syncthreads();

    // ---- Gather: out[fine] = w0*G[j0] + w1*G[j1] + w2*G[j2] + b ----
    const float4 bb = bias4[lane];
#pragma unroll
    for (int p = 0; p < 8; ++p) {
        int fl = wave * 8 + p;
        float w0 = swgt[fl * 3 + 0];
        float w1 = swgt[fl * 3 + 1];
        float w2 = swgt[fl * 3 + 2];
        int j0 = sidx[fl * 3 + 0];
        int j1 = sidx[fl * 3 + 1];
        int j2 = sidx[fl * 3 + 2];
        float4 g0 = G4[(size_t)j0 * 64 + lane];
        float4 g1 = G4[(size_t)j1 * 64 + lane];
        float4 g2 = G4[(size_t)j2 * 64 + lane];
        float4 o;
        o.x = fmaf(w0, g0.x, fmaf(w1, g1.x, fmaf(w2, g2.x, bb.x)));
        o.y = fmaf(w0, g0.y, fmaf(w1, g1.y, fmaf(w2, g2.y, bb.y)));
        o.z = fmaf(w0, g0.z, fmaf(w1, g1.z, fmaf(w2, g2.z, bb.z)));
        o.w = fmaf(w0, g0.w, fmaf(w1, g1.w, fmaf(w2, g2.w, bb.w)));
        out4[(size_t)(blockIdx.x * 64 + fl) * 64 + lane] = o;
    }
}

extern "C" void kernel_launch(void* const* d_in, const int* in_sizes, int n_in,
                              void* d_out, int out_size, void* d_ws, size_t ws_size,
                              hipStream_t stream) {
    const float* xyz1 = (const float*)d_in[0];
    const float* xyz2 = (const float*)d_in[1];
    // d_in[2] = feature1 (unused by the reference computation)
    const float* f2   = (const float*)d_in[3];
    const float* W    = (const float*)d_in[6];
    const float* bias = (const float*)d_in[7];

    const int N1  = in_sizes[0] / 3;   // 32768
    const int N2  = in_sizes[1] / 3;   // 8192
    const int C   = in_sizes[3] / N2;  // 256
    const int OUT = in_sizes[7];       // 256

    float*  G    = (float*)d_ws;                                   // N2*OUT f32 = 8 MB
    float4* pack = (float4*)((char*)d_ws + (size_t)N2 * OUT * 4);  // N2 float4 = 128 KB

    prep_kernel<<<(N2 + 255) / 256, 256, 0, stream>>>(xyz2, pack, N2);

    dim3 ggrid(N2 / 64, OUT / 64);
    gemm_nt_f32<<<ggrid, 256, 0, stream>>>(f2, W, G, N2, OUT, C);

    knn_gather<<<N1 / 64, 512, 0, stream>>>(xyz1, pack, (const float4*)G,
                                            (const float4*)bias, (float4*)d_out, N2);
}